// Round 1
// baseline (4739.862 us; speedup 1.0000x reference)
//
#include <hip/hip_runtime.h>
#include <math.h>
#include <stdint.h>

#define FMW 50
#define P_IMG 2500
#define CIN 512
#define NA 9
#define NANCH 22500
#define BATCH 16
#define PRE 512
#define POST 128
#define NCHUNK 44
#define NPAD (NCHUNK * 512)   // 22528
#define TILE_PX 64
#define NTILES 40             // ceil(2500/64)

// ---------------- K0: transpose w1 [co][ci][ky][kx] -> w1t [pos][ci][co] ----------------
__global__ void k_transpose_w1(const float* __restrict__ w1, float* __restrict__ w1t) {
    int e = blockIdx.x * 256 + threadIdx.x;        // 9*512*512 = 2359296 total
    int pos = e / (512 * 512);
    int rem = e - pos * 512 * 512;
    int ci = rem >> 9;
    int co = rem & 511;
    w1t[e] = w1[(co * 512 + ci) * 9 + pos];
}

// ---------------- K1: fused 3x3 conv + ReLU + 1x1 convs + score keys ----------------
// block: 64 pixels x 512 out-channels, 256 threads, 128 fp32 acc/thread
__global__ __launch_bounds__(256, 2)
void k_conv_fused(const float* __restrict__ fm, const float* __restrict__ w1t,
                  const float* __restrict__ b1, const float* __restrict__ w2,
                  const float* __restrict__ b2, const float* __restrict__ w3,
                  const float* __restrict__ b3,
                  float* __restrict__ off_ws, unsigned long long* __restrict__ keys) {
    __shared__ union {
        struct { float A[16 * 64]; float B[16 * 512]; } g;          // 36 KB
        struct { float SH[128 * 65]; float W[48 * 128]; } e;        // 57.3 KB
    } sm;

    const int t = threadIdx.x;
    const int img = blockIdx.x / NTILES;
    const int p0 = (blockIdx.x % NTILES) * TILE_PX;

    const int cg4 = (t & 31) * 4;   // channel group base within 128-block
    const int pg8 = (t >> 5) * 8;   // pixel group base (0..56)

    // A-load geometry (px fixed per thread; kc = t>>6 + 4i)
    const int pxa = t & 63;
    const int kca = t >> 6;
    const int pA = p0 + pxa;
    const bool pAvalid = pA < P_IMG;
    const int ya = pA / FMW;
    const int xa = pA - ya * FMW;
    // B-load geometry
    const int c4 = t & 127;
    const int kcb = t >> 7;

    float acc[8][16];
#pragma unroll
    for (int k = 0; k < 8; ++k)
#pragma unroll
        for (int j = 0; j < 16; ++j) acc[k][j] = 0.f;

    const size_t img_base = (size_t)img * CIN * P_IMG;

    for (int pos = 0; pos < 9; ++pos) {
        const int dy = pos / 3 - 1, dx = pos % 3 - 1;
        const int nya = ya + dy, nxa = xa + dx;
        const bool okA = pAvalid && ((unsigned)nya < (unsigned)FMW) && ((unsigned)nxa < (unsigned)FMW);
        const int nidx = nya * FMW + nxa;
        for (int ci0 = 0; ci0 < CIN; ci0 += 16) {
            __syncthreads();
#pragma unroll
            for (int i = 0; i < 4; ++i) {
                int kc = kca + i * 4;
                float v = 0.f;
                if (okA) v = fm[img_base + (size_t)(ci0 + kc) * P_IMG + nidx];
                sm.g.A[kc * 64 + pxa] = v;
            }
            const float4* bsrc = (const float4*)(w1t + (size_t)(pos * 512 + ci0) * 512);
#pragma unroll
            for (int i = 0; i < 8; ++i) {
                int kc = kcb + i * 2;
                float4 v = bsrc[kc * 128 + c4];
                *((float4*)(sm.g.B + kc * 512 + c4 * 4)) = v;
            }
            __syncthreads();
#pragma unroll
            for (int kc = 0; kc < 16; ++kc) {
                float a[8];
                float4 a0 = *(const float4*)(sm.g.A + kc * 64 + pg8);
                float4 a1 = *(const float4*)(sm.g.A + kc * 64 + pg8 + 4);
                a[0] = a0.x; a[1] = a0.y; a[2] = a0.z; a[3] = a0.w;
                a[4] = a1.x; a[5] = a1.y; a[6] = a1.z; a[7] = a1.w;
                float bv[16];
#pragma unroll
                for (int j = 0; j < 4; ++j) {
                    float4 b4 = *(const float4*)(sm.g.B + kc * 512 + j * 128 + cg4);
                    bv[j * 4 + 0] = b4.x; bv[j * 4 + 1] = b4.y;
                    bv[j * 4 + 2] = b4.z; bv[j * 4 + 3] = b4.w;
                }
#pragma unroll
                for (int k = 0; k < 8; ++k)
#pragma unroll
                    for (int j = 0; j < 16; ++j)
                        acc[k][j] = fmaf(a[k], bv[j], acc[k][j]);
            }
        }
    }

    // bias + relu (b1 is zeros in this problem but applied for generality)
#pragma unroll
    for (int j = 0; j < 4; ++j) {
        float4 bb = *(const float4*)(b1 + j * 128 + cg4);
        float bj[4] = {bb.x, bb.y, bb.z, bb.w};
#pragma unroll
        for (int k = 0; k < 8; ++k)
#pragma unroll
            for (int c = 0; c < 4; ++c)
                acc[k][j * 4 + c] = fmaxf(acc[k][j * 4 + c] + bj[c], 0.f);
    }

    // ---- fused 1x1 convs: out45[px][o] = sum_c sh[c][px]*w45[o][c], 4 rounds of 128 ch ----
    float p45[12];
#pragma unroll
    for (int m = 0; m < 12; ++m) p45[m] = 0.f;
    const int pxe = t & 63;
    const int og = t >> 6;   // 0..3 -> o = og*12 + m

    for (int r = 0; r < 4; ++r) {
        __syncthreads();
#pragma unroll
        for (int c = 0; c < 4; ++c)
#pragma unroll
            for (int k = 0; k < 8; ++k)
                sm.e.SH[(cg4 + c) * 65 + pg8 + k] = acc[k][r * 4 + c];
#pragma unroll
        for (int i = 0; i < 24; ++i) {
            int o = (t >> 7) + 2 * i;
            int cl = t & 127;
            float wv = 0.f;
            if (o < 9) wv = w2[o * 512 + r * 128 + cl];
            else if (o < 45) wv = w3[(o - 9) * 512 + r * 128 + cl];
            sm.e.W[o * 128 + cl] = wv;
        }
        __syncthreads();
        for (int cl = 0; cl < 128; ++cl) {
            float s = sm.e.SH[cl * 65 + pxe];
#pragma unroll
            for (int m = 0; m < 12; ++m)
                p45[m] = fmaf(s, sm.e.W[(og * 12 + m) * 128 + cl], p45[m]);
        }
    }

    const int pE = p0 + pxe;
    if (pE < P_IMG) {
#pragma unroll
        for (int m = 0; m < 12; ++m) {
            int o = og * 12 + m;
            if (o < 9) {
                float z = p45[m] + b2[o];
                float s = (z >= 0.f) ? (1.f / (1.f + expf(-z)))
                                     : (expf(z) / (1.f + expf(z)));
                unsigned n = (unsigned)(pE * 9 + o);
                unsigned long long key =
                    ((unsigned long long)__float_as_uint(s) << 32) |
                    (unsigned long long)(0xFFFFFFFFu - n);
                keys[(size_t)img * NPAD + n] = key;
            } else if (o < 45) {
                int c = o - 9;
                off_ws[((size_t)img * P_IMG + pE) * 36 + c] = p45[m] + b3[c];
            }
        }
    }
}

// ---------------- K2: bitonic sort each 512-chunk descending ----------------
__global__ __launch_bounds__(256)
void k_sort_chunks(unsigned long long* __restrict__ keys) {
    __shared__ unsigned long long sk[512];
    const int t = threadIdx.x;
    const int img = blockIdx.x / NCHUNK;
    const int ch = blockIdx.x % NCHUNK;
    const size_t base = (size_t)img * NPAD + ch * 512;
    sk[t] = keys[base + t];
    sk[t + 256] = keys[base + t + 256];
    for (int k = 2; k <= 512; k <<= 1)
        for (int j = k >> 1; j > 0; j >>= 1) {
            __syncthreads();
            for (int i = t; i < 512; i += 256) {
                int l = i ^ j;
                if (l > i) {
                    unsigned long long a = sk[i], b = sk[l];
                    bool desc = ((i & k) == 0);
                    if (desc ? (a < b) : (a > b)) { sk[i] = b; sk[l] = a; }
                }
            }
        }
    __syncthreads();
    keys[base + t] = sk[t];
    keys[base + t + 256] = sk[t + 256];
}

// ---------------- K3: per-image merge to top-512, decode, NMS, top-128, write ----------------
__global__ __launch_bounds__(256)
void k_nms(const unsigned long long* __restrict__ keys,
           const float* __restrict__ off_ws, float* __restrict__ out) {
    __shared__ unsigned long long top[512];
    __shared__ unsigned long long chk[512];
    __shared__ float bx1[512], by1[512], bx2[512], by2[512], bar[512], bsc[512];
    __shared__ int keep[512];

    const int t = threadIdx.x;
    const int img = blockIdx.x;
    const size_t kbase = (size_t)img * NPAD;

    top[t] = keys[kbase + t];
    top[t + 256] = keys[kbase + t + 256];

    // merge 43 more sorted chunks, keeping running top-512 (bitonic max-merge)
    for (int c = 1; c < NCHUNK; ++c) {
        __syncthreads();
        chk[t] = keys[kbase + c * 512 + t];
        chk[t + 256] = keys[kbase + c * 512 + t + 256];
        __syncthreads();
        for (int i = t; i < 512; i += 256) {
            unsigned long long a = top[i], b = chk[511 - i];
            top[i] = (a > b) ? a : b;
        }
        for (int j = 256; j > 0; j >>= 1) {
            __syncthreads();
            int i = ((t & ~(j - 1)) << 1) | (t & (j - 1));
            unsigned long long a = top[i], b = top[i + j];
            if (a < b) { top[i] = b; top[i + j] = a; }
        }
    }
    __syncthreads();

    // decode candidates: anchors in double (matches np), decode/clip in f32 (matches jax)
    for (int i = t; i < 512; i += 256) {
        unsigned long long key = top[i];
        float s = __uint_as_float((unsigned)(key >> 32));
        unsigned id = 0xFFFFFFFFu - (unsigned)(key & 0xFFFFFFFFull);
        float x1 = 0.f, y1 = 0.f, x2 = 0.f, y2 = 0.f;
        bool valid = false;
        if (key != 0ull && id < (unsigned)NANCH) {
            int p = id / 9, a = id - p * 9;
            int gy = p / FMW, gx = p - gy * FMW;
            const double SS[3] = {32.0, 64.0, 128.0};
            const double RR[3] = {0.5, 1.0, 2.0};
            double sq = sqrt(RR[a % 3]);
            float wa32 = (float)(SS[a / 3] / sq);
            float ha32 = (float)(SS[a / 3] * sq);
            double cx = ((double)gx + 0.5) * 16.0;
            double cy = ((double)gy + 0.5) * 16.0;
            float ax1 = (float)(cx - (double)(wa32 * 0.5f));
            float ay1 = (float)(cy - (double)(ha32 * 0.5f));
            float ax2 = (float)(cx + (double)(wa32 * 0.5f));
            float ay2 = (float)(cy + (double)(ha32 * 0.5f));
            float aw = ax2 - ax1, ah = ay2 - ay1;
            float acx = ax1 + 0.5f * aw, acy = ay1 + 0.5f * ah;
            const float4 off = *(const float4*)(off_ws + ((size_t)img * P_IMG + p) * 36 + a * 4);
            float px = acx + off.x * aw;
            float py = acy + off.y * ah;
            float pw = aw * expf(off.z);
            float ph = ah * expf(off.w);
            x1 = fminf(fmaxf(px - 0.5f * pw, 0.f), 800.f);
            y1 = fminf(fmaxf(py - 0.5f * ph, 0.f), 800.f);
            x2 = fminf(fmaxf(px + 0.5f * pw, 0.f), 800.f);
            y2 = fminf(fmaxf(py + 0.5f * ph, 0.f), 800.f);
            float w = x2 - x1, h = y2 - y1;
            valid = (w >= 1e-3f) && (h >= 1e-3f) && (s >= 0.5f);
        }
        bx1[i] = x1; by1[i] = y1; bx2[i] = x2; by2[i] = y2;
        bar[i] = (x2 - x1) * (y2 - y1);
        bsc[i] = s;
        keep[i] = valid ? 1 : 0;
    }
    __syncthreads();

    // greedy NMS over sorted candidates
    for (int i = 0; i < PRE - 1; ++i) {
        __syncthreads();
        if (keep[i] == 0) continue;
        float xi1 = bx1[i], yi1 = by1[i], xi2 = bx2[i], yi2 = by2[i], ai = bar[i];
        for (int j = i + 1 + t; j < PRE; j += 256) {
            if (keep[j]) {
                float lx = fmaxf(xi1, bx1[j]);
                float ly = fmaxf(yi1, by1[j]);
                float rx = fminf(xi2, bx2[j]);
                float ry = fminf(yi2, by2[j]);
                float iw = fmaxf(rx - lx, 0.f);
                float ih = fmaxf(ry - ly, 0.f);
                float inter = iw * ih;
                float iou = inter / (ai + bar[j] - inter + 1e-9f);
                if (iou > 0.7f) keep[j] = 0;
            }
        }
    }
    __syncthreads();

    // top-128 of masked scores (desc, stable by slot): 64-bit ordered keys
    for (int i = t; i < 512; i += 256) {
        float m = keep[i] ? bsc[i] : -1.0f;
        unsigned u = __float_as_uint(m);
        u = (u & 0x80000000u) ? ~u : (u | 0x80000000u);
        chk[i] = ((unsigned long long)u << 32) | (unsigned long long)(511 - i);
    }
    for (int k = 2; k <= 512; k <<= 1)
        for (int j = k >> 1; j > 0; j >>= 1) {
            __syncthreads();
            for (int i = t; i < 512; i += 256) {
                int l = i ^ j;
                if (l > i) {
                    unsigned long long a = chk[i], b = chk[l];
                    bool desc = ((i & k) == 0);
                    if (desc ? (a < b) : (a > b)) { chk[i] = b; chk[l] = a; }
                }
            }
        }
    __syncthreads();

    if (t < POST) {
        unsigned long long key = chk[t];
        int slot = 511 - (int)(key & 0xFFFFFFFFull);
        float m = keep[slot] ? bsc[slot] : -1.0f;
        bool ok = (m >= 0.5f);
        float* ob = out + ((size_t)img * POST + t) * 4;
        ob[0] = ok ? bx1[slot] : 0.f;
        ob[1] = ok ? by1[slot] : 0.f;
        ob[2] = ok ? bx2[slot] : 0.f;
        ob[3] = ok ? by2[slot] : 0.f;
        out[(size_t)BATCH * POST * 4 + img * POST + t] = ok ? m : 0.f;
    }
}

// ---------------- launcher ----------------
extern "C" void kernel_launch(void* const* d_in, const int* in_sizes, int n_in,
                              void* d_out, int out_size, void* d_ws, size_t ws_size,
                              hipStream_t stream) {
    const float* fm = (const float*)d_in[0];
    const float* w1 = (const float*)d_in[1];
    const float* b1 = (const float*)d_in[2];
    const float* w2 = (const float*)d_in[3];
    const float* b2 = (const float*)d_in[4];
    const float* w3 = (const float*)d_in[5];
    const float* b3 = (const float*)d_in[6];
    float* out = (float*)d_out;

    char* ws = (char*)d_ws;
    // ws layout: off_ws 5,760,000 B | keys @0x580000 (2,883,584 B) | w1t @0x840000 (9,437,184 B)
    float* off_ws = (float*)ws;
    unsigned long long* keys = (unsigned long long*)(ws + 0x580000);
    float* w1t = (float*)(ws + 0x840000);

    hipMemsetAsync(keys, 0, (size_t)BATCH * NPAD * sizeof(unsigned long long), stream);
    k_transpose_w1<<<(9 * 512 * 512) / 256, 256, 0, stream>>>(w1, w1t);
    k_conv_fused<<<BATCH * NTILES, 256, 0, stream>>>(fm, w1t, b1, w2, b2, w3, b3, off_ws, keys);
    k_sort_chunks<<<BATCH * NCHUNK, 256, 0, stream>>>(keys);
    k_nms<<<BATCH, 256, 0, stream>>>(keys, off_ws, out);
}

// Round 2
// 1748.415 us; speedup vs baseline: 2.7109x; 2.7109x over previous
//
#include <hip/hip_runtime.h>
#include <math.h>
#include <stdint.h>

#define FMW 50
#define P_IMG 2500
#define CIN 512
#define NANCH 22500
#define BATCH 16
#define PRE 512
#define POST 128
#define NCHUNK 44
#define NPAD (NCHUNK * 512)   // 22528

typedef __attribute__((ext_vector_type(8))) short short8;
typedef __attribute__((ext_vector_type(16))) float f32x16;

union U4S8 { uint4 u; short8 s; };

__device__ __forceinline__ unsigned short f2bf(float x) {
    unsigned u = __float_as_uint(x);
    unsigned r = u + 0x7FFFu + ((u >> 16) & 1u);
    return (unsigned short)(r >> 16);
}
__device__ __forceinline__ float bf2f(unsigned short h) {
    return __uint_as_float(((unsigned)h) << 16);
}

// ---------------- K0: prepack w1 -> bf16 hi/lo MFMA-fragment order ----------------
// layout: [pos(9)][c(32)][NT(16)][s(2)][lane(64)][8 bf16]  (1024 B per frag)
__global__ void k_prepack(const float* __restrict__ w1, char* __restrict__ w1pack) {
    int t = blockIdx.x * 256 + threadIdx.x;        // 9*32*16*64 = 294912
    int l = t & 63;
    int NT = (t >> 6) & 15;
    int c = (t >> 10) & 31;
    int pos = t >> 15;
    int oc = NT * 32 + (l & 31);
    unsigned short hv[8], lv[8];
#pragma unroll
    for (int j = 0; j < 8; ++j) {
        int ci = c * 16 + (l >> 5) * 8 + j;
        float x = w1[((size_t)oc * 512 + ci) * 9 + pos];
        unsigned short h = f2bf(x);
        hv[j] = h;
        lv[j] = f2bf(x - bf2f(h));
    }
    size_t base = ((size_t)((pos * 32 + c) * 16 + NT) * 2) * 1024 + (size_t)l * 16;
    uint4 hu, lu;
    hu.x = hv[0] | ((unsigned)hv[1] << 16); hu.y = hv[2] | ((unsigned)hv[3] << 16);
    hu.z = hv[4] | ((unsigned)hv[5] << 16); hu.w = hv[6] | ((unsigned)hv[7] << 16);
    lu.x = lv[0] | ((unsigned)lv[1] << 16); lu.y = lv[2] | ((unsigned)lv[3] << 16);
    lu.z = lv[4] | ((unsigned)lv[5] << 16); lu.w = lv[6] | ((unsigned)lv[7] << 16);
    *(uint4*)(w1pack + base) = hu;
    *(uint4*)(w1pack + base + 1024) = lu;
}

// ---------------- K1: MFMA conv (bf16 split, 3 products) + fused 1x1 epilogue ----------------
// block = 256 thr = 4 waves; block tile 128 px x 512 oc; wave tile 128 x 128.
__global__ __launch_bounds__(256, 1)
void k_conv_mfma(const float* __restrict__ fm, const char* __restrict__ w1pack,
                 const float* __restrict__ b1, const float* __restrict__ w2,
                 const float* __restrict__ b2, const float* __restrict__ w3,
                 const float* __restrict__ b3,
                 float* __restrict__ off_ws, unsigned long long* __restrict__ keys) {
    // A-window: [s(2)][kh(2)][px_local(256)][j(8)] bf16 = 16384 B (phase 1)
    // epilogue: SH[128 oc][129 px] f32 (66048) + W[48][128] f32 (24576) (phase 2)
    __shared__ __align__(16) char smem[90624];

    const int t = threadIdx.x;
    const int l = t & 63;
    const int w = t >> 6;
    const int blk = blockIdx.x;
    const int img = blk / 20;
    const int pt = blk % 20;
    const int p0 = pt * 128;

    f32x16 acc[4][4];
#pragma unroll
    for (int mt = 0; mt < 4; ++mt)
#pragma unroll
        for (int nt = 0; nt < 4; ++nt)
#pragma unroll
            for (int r = 0; r < 16; ++r) acc[mt][nt][r] = 0.f;

    int xs[4];
#pragma unroll
    for (int mt = 0; mt < 4; ++mt) xs[mt] = (p0 + mt * 32 + (l & 31)) % 50;

    const int aread_base = (l >> 5) * 4096 + (64 + (l & 31)) * 16;
    const size_t img_base = (size_t)img * CIN * P_IMG;
    const int DPOS[9] = {-51, -50, -49, -1, 0, 1, 49, 50, 51};

    for (int c = 0; c < 32; ++c) {
        const int ci0 = c * 16;
        __syncthreads();
        // ---- stage A window: px_local = t (0..255) <-> pw = p0-64+t ----
        {
            const int pw = p0 - 64 + t;
            const bool ok = (pw >= 0) && (pw < P_IMG);
#pragma unroll
            for (int cq = 0; cq < 4; ++cq) {
                float v[4];
#pragma unroll
                for (int q = 0; q < 4; ++q) {
                    int ci = ci0 + cq * 4 + q;
                    v[q] = ok ? fm[img_base + (size_t)ci * P_IMG + pw] : 0.f;
                }
                unsigned short h[4], lo[4];
#pragma unroll
                for (int q = 0; q < 4; ++q) {
                    h[q] = f2bf(v[q]);
                    lo[q] = f2bf(v[q] - bf2f(h[q]));
                }
                int kh = cq >> 1;
                int boff = kh * 4096 + t * 16 + (cq & 1) * 8;
                uint2 hu, lu;
                hu.x = h[0] | ((unsigned)h[1] << 16);  hu.y = h[2] | ((unsigned)h[3] << 16);
                lu.x = lo[0] | ((unsigned)lo[1] << 16); lu.y = lo[2] | ((unsigned)lo[3] << 16);
                *(uint2*)(smem + boff) = hu;
                *(uint2*)(smem + 8192 + boff) = lu;
            }
        }
        __syncthreads();

        for (int pos = 0; pos < 9; ++pos) {
            const int dpos = DPOS[pos];
            const int dx = pos % 3 - 1;
            // ---- B fragments direct from global (prepacked) ----
            U4S8 bh[4], bl[4];
            const char* bptr = w1pack + (size_t)(pos * 32 + c) * 32768
                               + (size_t)w * 8192 + (size_t)l * 16;
#pragma unroll
            for (int nt = 0; nt < 4; ++nt) {
                bh[nt].u = *(const uint4*)(bptr + nt * 2048);
                bl[nt].u = *(const uint4*)(bptr + nt * 2048 + 1024);
            }
            // ---- A fragments from LDS window (shifted) + x-edge mask ----
            U4S8 ah[4], al[4];
            const char* ap = smem + aread_base + dpos * 16;
#pragma unroll
            for (int mt = 0; mt < 4; ++mt) {
                ah[mt].u = *(const uint4*)(ap + mt * 512);
                al[mt].u = *(const uint4*)(ap + 8192 + mt * 512);
                bool xok = (dx == 0) || (dx < 0 ? (xs[mt] > 0) : (xs[mt] < 49));
                if (!xok) {
                    ah[mt].u.x = 0; ah[mt].u.y = 0; ah[mt].u.z = 0; ah[mt].u.w = 0;
                    al[mt].u.x = 0; al[mt].u.y = 0; al[mt].u.z = 0; al[mt].u.w = 0;
                }
            }
            // ---- 3-product split MFMA ----
#pragma unroll
            for (int nt = 0; nt < 4; ++nt)
#pragma unroll
                for (int mt = 0; mt < 4; ++mt) {
                    acc[mt][nt] = __builtin_amdgcn_mfma_f32_32x32x16_bf16(
                        ah[mt].s, bh[nt].s, acc[mt][nt], 0, 0, 0);
                    acc[mt][nt] = __builtin_amdgcn_mfma_f32_32x32x16_bf16(
                        al[mt].s, bh[nt].s, acc[mt][nt], 0, 0, 0);
                    acc[mt][nt] = __builtin_amdgcn_mfma_f32_32x32x16_bf16(
                        ah[mt].s, bl[nt].s, acc[mt][nt], 0, 0, 0);
                }
        }
    }

    // ---------------- fused 1x1 epilogue ----------------
    float* SH = (float*)smem;            // [128 oc][129 px]
    float* W = (float*)(smem + 66048);   // [48][128]
    float b1v[4];
#pragma unroll
    for (int nt = 0; nt < 4; ++nt) b1v[nt] = b1[(w * 4 + nt) * 32 + (l & 31)];

    const int pxe = t & 127;
    const int og = t >> 7;               // 0: o 0..22, 1: o 23..44
    const int no = og ? 22 : 23;
    float p45[23];
#pragma unroll
    for (int m = 0; m < 23; ++m) p45[m] = 0.f;

    for (int rr = 0; rr < 4; ++rr) {
        __syncthreads();
        // stage W for this oc-chunk
#pragma unroll
        for (int i = 0; i < 24; ++i) {
            int e = i * 256 + t;
            int o = e >> 7, cl = e & 127;
            float wv = 0.f;
            if (o < 9) wv = w2[o * 512 + rr * 128 + cl];
            else if (o < 45) wv = w3[(o - 9) * 512 + rr * 128 + cl];
            W[o * 128 + cl] = wv;
        }
        // wave rr writes relu(acc + b1) for its 128 oc
        if (w == rr) {
#pragma unroll
            for (int nt = 0; nt < 4; ++nt) {
                int oc_l = nt * 32 + (l & 31);
#pragma unroll
                for (int mt = 0; mt < 4; ++mt)
#pragma unroll
                    for (int r = 0; r < 16; ++r) {
                        int row = (r & 3) + 8 * (r >> 2) + 4 * (l >> 5);
                        SH[oc_l * 129 + mt * 32 + row] =
                            fmaxf(acc[mt][nt][r] + b1v[nt], 0.f);
                    }
            }
        }
        __syncthreads();
        for (int cl = 0; cl < 128; ++cl) {
            float sv = SH[cl * 129 + pxe];
#pragma unroll
            for (int m = 0; m < 23; ++m)
                if (m < no) p45[m] = fmaf(sv, W[(og * 23 + m) * 128 + cl], p45[m]);
        }
    }

    const int pE = p0 + pxe;
    if (pE < P_IMG) {
        for (int m = 0; m < no; ++m) {
            int o = og * 23 + m;
            if (o < 9) {
                float z = p45[m] + b2[o];
                float s = (z >= 0.f) ? (1.f / (1.f + expf(-z)))
                                     : (expf(z) / (1.f + expf(z)));
                unsigned n = (unsigned)(pE * 9 + o);
                unsigned long long key =
                    ((unsigned long long)__float_as_uint(s) << 32) |
                    (unsigned long long)(0xFFFFFFFFu - n);
                keys[(size_t)img * NPAD + n] = key;
            } else {
                int cc = o - 9;
                off_ws[((size_t)img * P_IMG + pE) * 36 + cc] = p45[m] + b3[cc];
            }
        }
    }
}

// ---------------- K2: bitonic sort each 512-chunk descending (verified V1) ----------------
__global__ __launch_bounds__(256)
void k_sort_chunks(unsigned long long* __restrict__ keys) {
    __shared__ unsigned long long sk[512];
    const int t = threadIdx.x;
    const int img = blockIdx.x / NCHUNK;
    const int ch = blockIdx.x % NCHUNK;
    const size_t base = (size_t)img * NPAD + ch * 512;
    sk[t] = keys[base + t];
    sk[t + 256] = keys[base + t + 256];
    for (int k = 2; k <= 512; k <<= 1)
        for (int j = k >> 1; j > 0; j >>= 1) {
            __syncthreads();
            for (int i = t; i < 512; i += 256) {
                int l = i ^ j;
                if (l > i) {
                    unsigned long long a = sk[i], b = sk[l];
                    bool desc = ((i & k) == 0);
                    if (desc ? (a < b) : (a > b)) { sk[i] = b; sk[l] = a; }
                }
            }
        }
    __syncthreads();
    keys[base + t] = sk[t];
    keys[base + t + 256] = sk[t + 256];
}

// ---------------- K3: merge top-512, decode, NMS, top-128 (verified V1) ----------------
__global__ __launch_bounds__(256)
void k_nms(const unsigned long long* __restrict__ keys,
           const float* __restrict__ off_ws, float* __restrict__ out) {
    __shared__ unsigned long long top[512];
    __shared__ unsigned long long chk[512];
    __shared__ float bx1[512], by1[512], bx2[512], by2[512], bar[512], bsc[512];
    __shared__ int keep[512];

    const int t = threadIdx.x;
    const int img = blockIdx.x;
    const size_t kbase = (size_t)img * NPAD;

    top[t] = keys[kbase + t];
    top[t + 256] = keys[kbase + t + 256];

    for (int c = 1; c < NCHUNK; ++c) {
        __syncthreads();
        chk[t] = keys[kbase + c * 512 + t];
        chk[t + 256] = keys[kbase + c * 512 + t + 256];
        __syncthreads();
        for (int i = t; i < 512; i += 256) {
            unsigned long long a = top[i], b = chk[511 - i];
            top[i] = (a > b) ? a : b;
        }
        for (int j = 256; j > 0; j >>= 1) {
            __syncthreads();
            int i = ((t & ~(j - 1)) << 1) | (t & (j - 1));
            unsigned long long a = top[i], b = top[i + j];
            if (a < b) { top[i] = b; top[i + j] = a; }
        }
    }
    __syncthreads();

    for (int i = t; i < 512; i += 256) {
        unsigned long long key = top[i];
        float s = __uint_as_float((unsigned)(key >> 32));
        unsigned id = 0xFFFFFFFFu - (unsigned)(key & 0xFFFFFFFFull);
        float x1 = 0.f, y1 = 0.f, x2 = 0.f, y2 = 0.f;
        bool valid = false;
        if (key != 0ull && id < (unsigned)NANCH) {
            int p = id / 9, a = id - p * 9;
            int gy = p / FMW, gx = p - gy * FMW;
            const double SS[3] = {32.0, 64.0, 128.0};
            const double RR[3] = {0.5, 1.0, 2.0};
            double sq = sqrt(RR[a % 3]);
            float wa32 = (float)(SS[a / 3] / sq);
            float ha32 = (float)(SS[a / 3] * sq);
            double cx = ((double)gx + 0.5) * 16.0;
            double cy = ((double)gy + 0.5) * 16.0;
            float ax1 = (float)(cx - (double)(wa32 * 0.5f));
            float ay1 = (float)(cy - (double)(ha32 * 0.5f));
            float ax2 = (float)(cx + (double)(wa32 * 0.5f));
            float ay2 = (float)(cy + (double)(ha32 * 0.5f));
            float aw = ax2 - ax1, ah = ay2 - ay1;
            float acx = ax1 + 0.5f * aw, acy = ay1 + 0.5f * ah;
            const float4 off = *(const float4*)(off_ws + ((size_t)img * P_IMG + p) * 36 + a * 4);
            float px = acx + off.x * aw;
            float py = acy + off.y * ah;
            float pw = aw * expf(off.z);
            float ph = ah * expf(off.w);
            x1 = fminf(fmaxf(px - 0.5f * pw, 0.f), 800.f);
            y1 = fminf(fmaxf(py - 0.5f * ph, 0.f), 800.f);
            x2 = fminf(fmaxf(px + 0.5f * pw, 0.f), 800.f);
            y2 = fminf(fmaxf(py + 0.5f * ph, 0.f), 800.f);
            float ww = x2 - x1, hh = y2 - y1;
            valid = (ww >= 1e-3f) && (hh >= 1e-3f) && (s >= 0.5f);
        }
        bx1[i] = x1; by1[i] = y1; bx2[i] = x2; by2[i] = y2;
        bar[i] = (x2 - x1) * (y2 - y1);
        bsc[i] = s;
        keep[i] = valid ? 1 : 0;
    }
    __syncthreads();

    for (int i = 0; i < PRE - 1; ++i) {
        __syncthreads();
        if (keep[i] == 0) continue;
        float xi1 = bx1[i], yi1 = by1[i], xi2 = bx2[i], yi2 = by2[i], ai = bar[i];
        for (int j = i + 1 + t; j < PRE; j += 256) {
            if (keep[j]) {
                float lx = fmaxf(xi1, bx1[j]);
                float ly = fmaxf(yi1, by1[j]);
                float rx = fminf(xi2, bx2[j]);
                float ry = fminf(yi2, by2[j]);
                float iw = fmaxf(rx - lx, 0.f);
                float ih = fmaxf(ry - ly, 0.f);
                float inter = iw * ih;
                float iou = inter / (ai + bar[j] - inter + 1e-9f);
                if (iou > 0.7f) keep[j] = 0;
            }
        }
    }
    __syncthreads();

    for (int i = t; i < 512; i += 256) {
        float m = keep[i] ? bsc[i] : -1.0f;
        unsigned u = __float_as_uint(m);
        u = (u & 0x80000000u) ? ~u : (u | 0x80000000u);
        chk[i] = ((unsigned long long)u << 32) | (unsigned long long)(511 - i);
    }
    for (int k = 2; k <= 512; k <<= 1)
        for (int j = k >> 1; j > 0; j >>= 1) {
            __syncthreads();
            for (int i = t; i < 512; i += 256) {
                int l = i ^ j;
                if (l > i) {
                    unsigned long long a = chk[i], b = chk[l];
                    bool desc = ((i & k) == 0);
                    if (desc ? (a < b) : (a > b)) { chk[i] = b; chk[l] = a; }
                }
            }
        }
    __syncthreads();

    if (t < POST) {
        unsigned long long key = chk[t];
        int slot = 511 - (int)(key & 0xFFFFFFFFull);
        float m = keep[slot] ? bsc[slot] : -1.0f;
        bool ok = (m >= 0.5f);
        float* ob = out + ((size_t)img * POST + t) * 4;
        ob[0] = ok ? bx1[slot] : 0.f;
        ob[1] = ok ? by1[slot] : 0.f;
        ob[2] = ok ? bx2[slot] : 0.f;
        ob[3] = ok ? by2[slot] : 0.f;
        out[(size_t)BATCH * POST * 4 + img * POST + t] = ok ? m : 0.f;
    }
}

// ---------------- launcher ----------------
extern "C" void kernel_launch(void* const* d_in, const int* in_sizes, int n_in,
                              void* d_out, int out_size, void* d_ws, size_t ws_size,
                              hipStream_t stream) {
    const float* fm = (const float*)d_in[0];
    const float* w1 = (const float*)d_in[1];
    const float* b1 = (const float*)d_in[2];
    const float* w2 = (const float*)d_in[3];
    const float* b2 = (const float*)d_in[4];
    const float* w3 = (const float*)d_in[5];
    const float* b3 = (const float*)d_in[6];
    float* out = (float*)d_out;

    char* ws = (char*)d_ws;
    // ws layout (peak 18,087,936 B — identical to V1's proven footprint):
    //   [0, 0x900000)           w1pack  (9,437,184 B)
    //   [0x900000, +5,760,000)  off_ws
    //   [0xE80000, +2,883,584)  keys
    char* w1pack = ws;
    float* off_ws = (float*)(ws + 0x900000);
    unsigned long long* keys = (unsigned long long*)(ws + 0xE80000);

    hipMemsetAsync(keys, 0, (size_t)BATCH * NPAD * sizeof(unsigned long long), stream);
    k_prepack<<<1152, 256, 0, stream>>>(w1, w1pack);
    k_conv_mfma<<<BATCH * 20, 256, 0, stream>>>(fm, w1pack, b1, w2, b2, w3, b3, off_ws, keys);
    k_sort_chunks<<<BATCH * NCHUNK, 256, 0, stream>>>(keys);
    k_nms<<<BATCH, 256, 0, stream>>>(keys, off_ws, out);
}

// Round 3
// 1131.469 us; speedup vs baseline: 4.1891x; 1.5453x over previous
//
#include <hip/hip_runtime.h>
#include <math.h>
#include <stdint.h>

#define FMW 50
#define P_IMG 2500
#define CIN 512
#define NANCH 22500
#define BATCH 16
#define PRE 512
#define POST 128
#define NCHUNK 44
#define NPAD (NCHUNK * 512)   // 22528
#define MB 192                // block px tile
#define NTIL 14               // ceil(2500/192)
#define WIN 320               // A halo window (64 + 192 + 64)

typedef __attribute__((ext_vector_type(8))) short short8;
typedef __attribute__((ext_vector_type(16))) float f32x16;

union U4S8 { uint4 u; short8 s; };

__device__ __forceinline__ unsigned short f2bf(float x) {
    unsigned u = __float_as_uint(x);
    unsigned r = u + 0x7FFFu + ((u >> 16) & 1u);
    return (unsigned short)(r >> 16);
}
__device__ __forceinline__ float bf2f(unsigned short h) {
    return __uint_as_float(((unsigned)h) << 16);
}

__device__ __forceinline__ void gload_lds16(const void* g, void* l) {
    __builtin_amdgcn_global_load_lds(
        (const __attribute__((address_space(1))) void*)g,
        (__attribute__((address_space(3))) void*)l, 16, 0, 0);
}

// ---------------- K0: prepack w1 -> bf16 hi/lo MFMA-fragment order (V2, verified) ----
// layout: [pos(9)][c(32)][NT(16)][s(2)][lane(64)][8 bf16]
__global__ void k_prepack(const float* __restrict__ w1, char* __restrict__ w1pack) {
    int t = blockIdx.x * 256 + threadIdx.x;        // 9*32*16*64 = 294912
    int l = t & 63;
    int NT = (t >> 6) & 15;
    int c = (t >> 10) & 31;
    int pos = t >> 15;
    int oc = NT * 32 + (l & 31);
    unsigned short hv[8], lv[8];
#pragma unroll
    for (int j = 0; j < 8; ++j) {
        int ci = c * 16 + (l >> 5) * 8 + j;
        float x = w1[((size_t)oc * 512 + ci) * 9 + pos];
        unsigned short h = f2bf(x);
        hv[j] = h;
        lv[j] = f2bf(x - bf2f(h));
    }
    size_t base = ((size_t)((pos * 32 + c) * 16 + NT) * 2) * 1024 + (size_t)l * 16;
    uint4 hu, lu;
    hu.x = hv[0] | ((unsigned)hv[1] << 16); hu.y = hv[2] | ((unsigned)hv[3] << 16);
    hu.z = hv[4] | ((unsigned)hv[5] << 16); hu.w = hv[6] | ((unsigned)hv[7] << 16);
    lu.x = lv[0] | ((unsigned)lv[1] << 16); lu.y = lv[2] | ((unsigned)lv[3] << 16);
    lu.z = lv[4] | ((unsigned)lv[5] << 16); lu.w = lv[6] | ((unsigned)lv[7] << 16);
    *(uint4*)(w1pack + base) = hu;
    *(uint4*)(w1pack + base + 1024) = lu;
}

// ---------------- K1: MFMA conv, 8 waves, 2/SIMD, B dbuf via global_load_lds ------
// block tile 192 px x 512 oc; wave (r=w>>2, q=w&3) tile 96 px x 128 oc.
__global__ __launch_bounds__(512, 2)
void k_conv_mfma(const float* __restrict__ fm, const char* __restrict__ w1pack,
                 const float* __restrict__ b1, const float* __restrict__ w2,
                 const float* __restrict__ b2, const float* __restrict__ w3,
                 const float* __restrict__ b3,
                 float* __restrict__ off_ws, unsigned long long* __restrict__ keys) {
    // phase1: A-window 20480 B @0  |  Bbuf0 32768 @20480  |  Bbuf1 32768 @53248
    // phase2: SH[128][193] f32 98816 @0  |  W[48][128] f32 24576 @98816
    __shared__ __align__(16) char smem[123392];

    const int t = threadIdx.x;
    const int l = t & 63;
    const int w = t >> 6;     // 0..7
    const int r = w >> 2;     // px-row 0..1
    const int q = w & 3;      // oc-col 0..3
    const int img = blockIdx.x / NTIL;
    const int p0 = (blockIdx.x % NTIL) * MB;

    f32x16 acc[3][4];
#pragma unroll
    for (int mt = 0; mt < 3; ++mt)
#pragma unroll
        for (int nt = 0; nt < 4; ++nt)
#pragma unroll
            for (int g = 0; g < 16; ++g) acc[mt][nt][g] = 0.f;

    int xs[3];
#pragma unroll
    for (int mt = 0; mt < 3; ++mt) xs[mt] = (p0 + r * 96 + mt * 32 + (l & 31)) % FMW;

    // A layout: byte = s*10240 + px*32 + (l>>5)*16 + j*2   (px in [0,320))
    const int arb = (64 + r * 96 + (l & 31)) * 32 + (l >> 5) * 16;
    const size_t img_base = (size_t)img * CIN * P_IMG;
    const int DPOS[9] = {-51, -50, -49, -1, 0, 1, 49, 50, 51};

    char* Abuf = smem;
    char* Bb0 = smem + 20480;
    char* Bb1 = smem + 53248;

    // stage A window for ci-chunk cc (320 px x 16 ci, hi/lo)
    auto stageA = [&](int cc) {
#pragma unroll
        for (int i = 0; i < 3; ++i) {
            int flat = i * 512 + t;          // (px, ci-quarter), 320*4 = 1280
            if (flat < 1280) {
                int qq = flat & 3;
                int pxl = flat >> 2;
                int pw = p0 - 64 + pxl;
                bool ok = (pw >= 0) && (pw < P_IMG);
                float v[4];
#pragma unroll
                for (int k = 0; k < 4; ++k)
                    v[k] = ok ? fm[img_base + (size_t)(cc * 16 + qq * 4 + k) * P_IMG + pw] : 0.f;
                unsigned short h[4], lo[4];
#pragma unroll
                for (int k = 0; k < 4; ++k) {
                    h[k] = f2bf(v[k]);
                    lo[k] = f2bf(v[k] - bf2f(h[k]));
                }
                uint2 hu, lu;
                hu.x = h[0] | ((unsigned)h[1] << 16);  hu.y = h[2] | ((unsigned)h[3] << 16);
                lu.x = lo[0] | ((unsigned)lo[1] << 16); lu.y = lo[2] | ((unsigned)lo[3] << 16);
                *(uint2*)(Abuf + pxl * 32 + qq * 8) = hu;
                *(uint2*)(Abuf + 10240 + pxl * 32 + qq * 8) = lu;
            }
        }
    };

    // async-stage B tile for iteration kk into buffer (kk&1): 32 KB, 4 chunks/wave
    auto stageB = [&](int kk) {
        int c = kk / 9, pos = kk % 9;
        const char* src = w1pack + (size_t)(pos * 32 + c) * 32768;
        char* dst = (kk & 1) ? Bb1 : Bb0;
#pragma unroll
        for (int j = 0; j < 4; ++j) {
            int chunk = w * 4 + j;
            gload_lds16(src + chunk * 1024 + l * 16, dst + chunk * 1024);
        }
    };

    stageB(0);
    stageA(0);
    __syncthreads();

    for (int kk = 0; kk < 288; ++kk) {
        const int c = kk / 9, pos = kk % 9;
        if (kk + 1 < 288) stageB(kk + 1);

        // ---- compute (c, pos) from Abuf + Bbuf[kk&1] ----
        const int dpos = DPOS[pos];
        const int dx = pos % 3 - 1;
        U4S8 ah[3], al[3];
        const char* ap = Abuf + arb + dpos * 32;
#pragma unroll
        for (int mt = 0; mt < 3; ++mt) {
            ah[mt].u = *(const uint4*)(ap + mt * 1024);
            al[mt].u = *(const uint4*)(ap + 10240 + mt * 1024);
            bool xok = (dx == 0) || (dx < 0 ? (xs[mt] > 0) : (xs[mt] < FMW - 1));
            if (!xok) {
                ah[mt].u.x = 0; ah[mt].u.y = 0; ah[mt].u.z = 0; ah[mt].u.w = 0;
                al[mt].u.x = 0; al[mt].u.y = 0; al[mt].u.z = 0; al[mt].u.w = 0;
            }
        }
        const char* bp = ((kk & 1) ? Bb1 : Bb0) + q * 8192 + l * 16;
#pragma unroll
        for (int nt = 0; nt < 4; ++nt) {
            U4S8 bh, bl;
            bh.u = *(const uint4*)(bp + nt * 2048);
            bl.u = *(const uint4*)(bp + nt * 2048 + 1024);
#pragma unroll
            for (int mt = 0; mt < 3; ++mt) {
                acc[mt][nt] = __builtin_amdgcn_mfma_f32_32x32x16_bf16(ah[mt].s, bh.s, acc[mt][nt], 0, 0, 0);
                acc[mt][nt] = __builtin_amdgcn_mfma_f32_32x32x16_bf16(al[mt].s, bh.s, acc[mt][nt], 0, 0, 0);
                acc[mt][nt] = __builtin_amdgcn_mfma_f32_32x32x16_bf16(ah[mt].s, bl.s, acc[mt][nt], 0, 0, 0);
            }
        }

        if (pos == 8 && c < 31) {
            __syncthreads();      // everyone done reading Abuf for chunk c
            stageA(c + 1);
        }
        __syncthreads();          // drains stageB(kk+1) (vmcnt) + A writes
    }

    // ---------------- fused 1x1 epilogue ----------------
    float* SH = (float*)smem;              // [128 oc][193 px]
    float* W  = (float*)(smem + 98816);    // [48][128]
    float b1v[4];
#pragma unroll
    for (int nt = 0; nt < 4; ++nt) b1v[nt] = b1[q * 128 + nt * 32 + (l & 31)];

    const int pxe = t % 192;
    const int og = t / 192;                // 0,1 active; 2 idle in dot
    const int no = (og == 0) ? 23 : 22;
    float p45[23];
#pragma unroll
    for (int m = 0; m < 23; ++m) p45[m] = 0.f;

    for (int rr = 0; rr < 4; ++rr) {
        __syncthreads();
        // stage W for oc-chunk rr (45 x 128)
#pragma unroll
        for (int i = 0; i < 12; ++i) {
            int e = i * 512 + t;
            if (e < 5760) {
                int o = e >> 7, cl = e & 127;
                W[o * 128 + cl] = (o < 9) ? w2[o * 512 + rr * 128 + cl]
                                          : w3[(o - 9) * 512 + rr * 128 + cl];
            }
        }
        // waves with q == rr write relu(acc + b1) for oc-chunk rr
        if (q == rr) {
#pragma unroll
            for (int nt = 0; nt < 4; ++nt) {
                int oc_l = nt * 32 + (l & 31);
#pragma unroll
                for (int mt = 0; mt < 3; ++mt)
#pragma unroll
                    for (int g = 0; g < 16; ++g) {
                        int row = (g & 3) + 8 * (g >> 2) + 4 * (l >> 5);
                        SH[oc_l * 193 + r * 96 + mt * 32 + row] =
                            fmaxf(acc[mt][nt][g] + b1v[nt], 0.f);
                    }
            }
        }
        __syncthreads();
        if (og < 2) {
            for (int cl = 0; cl < 128; ++cl) {
                float sv = SH[cl * 193 + pxe];
#pragma unroll
                for (int m = 0; m < 23; ++m)
                    if (m < no) p45[m] = fmaf(sv, W[(og * 23 + m) * 128 + cl], p45[m]);
            }
        }
    }

    const int pE = p0 + pxe;
    if (og < 2 && pE < P_IMG) {
        for (int m = 0; m < no; ++m) {
            int o = og * 23 + m;
            if (o < 9) {
                float z = p45[m] + b2[o];
                float s = (z >= 0.f) ? (1.f / (1.f + expf(-z)))
                                     : (expf(z) / (1.f + expf(z)));
                unsigned n = (unsigned)(pE * 9 + o);
                unsigned long long key =
                    ((unsigned long long)__float_as_uint(s) << 32) |
                    (unsigned long long)(0xFFFFFFFFu - n);
                keys[(size_t)img * NPAD + n] = key;
            } else {
                int cc = o - 9;
                off_ws[((size_t)img * P_IMG + pE) * 36 + cc] = p45[m] + b3[cc];
            }
        }
    }
}

// ---------------- K2: bitonic sort each 512-chunk descending (pad-guarded) --------
__global__ __launch_bounds__(256)
void k_sort_chunks(unsigned long long* __restrict__ keys) {
    __shared__ unsigned long long sk[512];
    const int t = threadIdx.x;
    const int img = blockIdx.x / NCHUNK;
    const int ch = blockIdx.x % NCHUNK;
    const size_t base = (size_t)img * NPAD + ch * 512;
    int a0 = ch * 512 + t, a1 = ch * 512 + t + 256;
    sk[t] = (a0 < NANCH) ? keys[base + t] : 0ull;
    sk[t + 256] = (a1 < NANCH) ? keys[base + t + 256] : 0ull;
    for (int k = 2; k <= 512; k <<= 1)
        for (int j = k >> 1; j > 0; j >>= 1) {
            __syncthreads();
            for (int i = t; i < 512; i += 256) {
                int lx = i ^ j;
                if (lx > i) {
                    unsigned long long a = sk[i], b = sk[lx];
                    bool desc = ((i & k) == 0);
                    if (desc ? (a < b) : (a > b)) { sk[i] = b; sk[lx] = a; }
                }
            }
        }
    __syncthreads();
    keys[base + t] = sk[t];
    keys[base + t + 256] = sk[t + 256];
}

// ---------------- K3: merge top-512, decode, NMS, top-128 (verified V1/V2) --------
__global__ __launch_bounds__(256)
void k_nms(const unsigned long long* __restrict__ keys,
           const float* __restrict__ off_ws, float* __restrict__ out) {
    __shared__ unsigned long long top[512];
    __shared__ unsigned long long chk[512];
    __shared__ float bx1[512], by1[512], bx2[512], by2[512], bar[512], bsc[512];
    __shared__ int keep[512];

    const int t = threadIdx.x;
    const int img = blockIdx.x;
    const size_t kbase = (size_t)img * NPAD;

    top[t] = keys[kbase + t];
    top[t + 256] = keys[kbase + t + 256];

    for (int c = 1; c < NCHUNK; ++c) {
        __syncthreads();
        chk[t] = keys[kbase + c * 512 + t];
        chk[t + 256] = keys[kbase + c * 512 + t + 256];
        __syncthreads();
        for (int i = t; i < 512; i += 256) {
            unsigned long long a = top[i], b = chk[511 - i];
            top[i] = (a > b) ? a : b;
        }
        for (int j = 256; j > 0; j >>= 1) {
            __syncthreads();
            int i = ((t & ~(j - 1)) << 1) | (t & (j - 1));
            unsigned long long a = top[i], b = top[i + j];
            if (a < b) { top[i] = b; top[i + j] = a; }
        }
    }
    __syncthreads();

    for (int i = t; i < 512; i += 256) {
        unsigned long long key = top[i];
        float s = __uint_as_float((unsigned)(key >> 32));
        unsigned id = 0xFFFFFFFFu - (unsigned)(key & 0xFFFFFFFFull);
        float x1 = 0.f, y1 = 0.f, x2 = 0.f, y2 = 0.f;
        bool valid = false;
        if (key != 0ull && id < (unsigned)NANCH) {
            int p = id / 9, a = id - p * 9;
            int gy = p / FMW, gx = p - gy * FMW;
            const double SS[3] = {32.0, 64.0, 128.0};
            const double RR[3] = {0.5, 1.0, 2.0};
            double sq = sqrt(RR[a % 3]);
            float wa32 = (float)(SS[a / 3] / sq);
            float ha32 = (float)(SS[a / 3] * sq);
            double cx = ((double)gx + 0.5) * 16.0;
            double cy = ((double)gy + 0.5) * 16.0;
            float ax1 = (float)(cx - (double)(wa32 * 0.5f));
            float ay1 = (float)(cy - (double)(ha32 * 0.5f));
            float ax2 = (float)(cx + (double)(wa32 * 0.5f));
            float ay2 = (float)(cy + (double)(ha32 * 0.5f));
            float aw = ax2 - ax1, ah2 = ay2 - ay1;
            float acx = ax1 + 0.5f * aw, acy = ay1 + 0.5f * ah2;
            const float4 off = *(const float4*)(off_ws + ((size_t)img * P_IMG + p) * 36 + a * 4);
            float px = acx + off.x * aw;
            float py = acy + off.y * ah2;
            float pw = aw * expf(off.z);
            float ph = ah2 * expf(off.w);
            x1 = fminf(fmaxf(px - 0.5f * pw, 0.f), 800.f);
            y1 = fminf(fmaxf(py - 0.5f * ph, 0.f), 800.f);
            x2 = fminf(fmaxf(px + 0.5f * pw, 0.f), 800.f);
            y2 = fminf(fmaxf(py + 0.5f * ph, 0.f), 800.f);
            float ww = x2 - x1, hh = y2 - y1;
            valid = (ww >= 1e-3f) && (hh >= 1e-3f) && (s >= 0.5f);
        }
        bx1[i] = x1; by1[i] = y1; bx2[i] = x2; by2[i] = y2;
        bar[i] = (x2 - x1) * (y2 - y1);
        bsc[i] = s;
        keep[i] = valid ? 1 : 0;
    }
    __syncthreads();

    for (int i = 0; i < PRE - 1; ++i) {
        __syncthreads();
        if (keep[i] == 0) continue;
        float xi1 = bx1[i], yi1 = by1[i], xi2 = bx2[i], yi2 = by2[i], ai = bar[i];
        for (int j = i + 1 + t; j < PRE; j += 256) {
            if (keep[j]) {
                float lx = fmaxf(xi1, bx1[j]);
                float ly = fmaxf(yi1, by1[j]);
                float rx = fminf(xi2, bx2[j]);
                float ry = fminf(yi2, by2[j]);
                float iw = fmaxf(rx - lx, 0.f);
                float ih = fmaxf(ry - ly, 0.f);
                float inter = iw * ih;
                float iou = inter / (ai + bar[j] - inter + 1e-9f);
                if (iou > 0.7f) keep[j] = 0;
            }
        }
    }
    __syncthreads();

    for (int i = t; i < 512; i += 256) {
        float m = keep[i] ? bsc[i] : -1.0f;
        unsigned u = __float_as_uint(m);
        u = (u & 0x80000000u) ? ~u : (u | 0x80000000u);
        chk[i] = ((unsigned long long)u << 32) | (unsigned long long)(511 - i);
    }
    for (int k = 2; k <= 512; k <<= 1)
        for (int j = k >> 1; j > 0; j >>= 1) {
            __syncthreads();
            for (int i = t; i < 512; i += 256) {
                int lx = i ^ j;
                if (lx > i) {
                    unsigned long long a = chk[i], b = chk[lx];
                    bool desc = ((i & k) == 0);
                    if (desc ? (a < b) : (a > b)) { chk[i] = b; chk[lx] = a; }
                }
            }
        }
    __syncthreads();

    if (t < POST) {
        unsigned long long key = chk[t];
        int slot = 511 - (int)(key & 0xFFFFFFFFull);
        float m = keep[slot] ? bsc[slot] : -1.0f;
        bool ok = (m >= 0.5f);
        float* ob = out + ((size_t)img * POST + t) * 4;
        ob[0] = ok ? bx1[slot] : 0.f;
        ob[1] = ok ? by1[slot] : 0.f;
        ob[2] = ok ? bx2[slot] : 0.f;
        ob[3] = ok ? by2[slot] : 0.f;
        out[(size_t)BATCH * POST * 4 + img * POST + t] = ok ? m : 0.f;
    }
}

// ---------------- launcher ----------------
extern "C" void kernel_launch(void* const* d_in, const int* in_sizes, int n_in,
                              void* d_out, int out_size, void* d_ws, size_t ws_size,
                              hipStream_t stream) {
    const float* fm = (const float*)d_in[0];
    const float* w1 = (const float*)d_in[1];
    const float* b1 = (const float*)d_in[2];
    const float* w2 = (const float*)d_in[3];
    const float* b2 = (const float*)d_in[4];
    const float* w3 = (const float*)d_in[5];
    const float* b3 = (const float*)d_in[6];
    float* out = (float*)d_out;

    char* ws = (char*)d_ws;
    // ws layout (18,087,936 B — identical to V2's proven footprint):
    //   [0, 0x900000)           w1pack  (9,437,184 B)
    //   [0x900000, +5,760,000)  off_ws
    //   [0xE80000, +2,883,584)  keys
    char* w1pack = ws;
    float* off_ws = (float*)(ws + 0x900000);
    unsigned long long* keys = (unsigned long long*)(ws + 0xE80000);

    k_prepack<<<1152, 256, 0, stream>>>(w1, w1pack);
    k_conv_mfma<<<BATCH * NTIL, 512, 0, stream>>>(fm, w1pack, b1, w2, b2, w3, b3, off_ws, keys);
    k_sort_chunks<<<BATCH * NCHUNK, 256, 0, stream>>>(keys);
    k_nms<<<BATCH, 256, 0, stream>>>(keys, off_ws, out);
}